// Round 6
// baseline (76.496 us; speedup 1.0000x reference)
//
#include <hip/hip_runtime.h>

#define BN 512   // batch
#define DD 512   // feature dim
#define LL 24    // label dim

typedef unsigned short u16;
typedef __attribute__((ext_vector_type(8))) short short8;  // 8 bf16 = 4 VGPR
typedef __attribute__((ext_vector_type(4))) float f32x4;

// ws layout (float words):
//   [0,512)              masks (u32)
//   [512, 512+262144)    Dm (f32, 512x512)
//   [262656]             accum: [0]=sum(f32) [1]=cnt(u32)

__device__ __forceinline__ u16 bf16_rn(float f) {
    unsigned u = __float_as_uint(f);
    return (u16)((u + 0x7FFFu + ((u >> 16) & 1u)) >> 16);
}
__device__ __forceinline__ float bf16_f(u16 h) {
    return __uint_as_float(((unsigned)h) << 16);
}

__device__ __forceinline__ float dist_val(float d2, bool diag) {
    d2 = fmaxf(d2, 0.0f);
    float d = sqrtf(d2);
    return diag ? 0.0f : d;
}

// split 8 f32 -> hi/lo bf16 fragments, accumulate sum of squares
__device__ __forceinline__ void split8(float4 x, float4 y, short8& h, short8& l, float& nrm) {
    float f[8] = {x.x, x.y, x.z, x.w, y.x, y.y, y.z, y.w};
#pragma unroll
    for (int e = 0; e < 8; e++) {
        nrm = fmaf(f[e], f[e], nrm);
        u16 hb = bf16_rn(f[e]);
        u16 lb = bf16_rn(f[e] - bf16_f(hb));
        h[e] = (short)hb;
        l[e] = (short)lb;
    }
}

// ---------- kernel 1: fused prep + MFMA dist (f32 in, split in-register) -----
__global__ __launch_bounds__(64) void dist_fused_kernel(
    const float* __restrict__ S, const int* __restrict__ labels,
    unsigned* __restrict__ masks, float* __restrict__ Dm, float* __restrict__ accum)
{
    const int l    = threadIdx.x;
    const int r    = l & 15;        // fragment row (A.m / B.n), also C.col
    const int half = l >> 4;        // k-base half*8; C.row base half*4
    const int jb = blockIdx.x * 32;
    const int ib = blockIdx.y * 32;
    const int kb = half * 8;

    // masks (y==0 blocks, 32 rows each) + accum zero (block 0,0)
    if (blockIdx.y == 0) {
        if (l < 32) {
            const int row = blockIdx.x * 32 + l;
            const int* lab = labels + row * LL;
            unsigned m = 0;
#pragma unroll
            for (int q = 0; q < LL; q++) m |= (lab[q] != 0 ? 1u : 0u) << q;
            masks[row] = m;
        }
        if (blockIdx.x == 0 && l == 0) { accum[0] = 0.0f; ((unsigned*)accum)[1] = 0u; }
    }

    const float* pA0 = S + (size_t)(ib + r)      * DD + kb;
    const float* pA1 = S + (size_t)(ib + 16 + r) * DD + kb;
    const float* pB0 = S + (size_t)(jb + r)      * DD + kb;
    const float* pB1 = S + (size_t)(jb + 16 + r) * DD + kb;

    f32x4 acc00 = {0.f,0.f,0.f,0.f}, acc01 = acc00, acc10 = acc00, acc11 = acc00;
    float nA0 = 0.f, nA1 = 0.f, nB0 = 0.f, nB1 = 0.f;

    float4 a0x = *(const float4*)pA0, a0y = *(const float4*)(pA0 + 4);
    float4 a1x = *(const float4*)pA1, a1y = *(const float4*)(pA1 + 4);
    float4 b0x = *(const float4*)pB0, b0y = *(const float4*)(pB0 + 4);
    float4 b1x = *(const float4*)pB1, b1y = *(const float4*)(pB1 + 4);

    for (int k0 = 0; k0 < DD; k0 += 32) {
        float4 na0x, na0y, na1x, na1y, nb0x, nb0y, nb1x, nb1y;
        const int kn = k0 + 32;
        if (kn < DD) {              // uniform: prefetch next k-step
            na0x = *(const float4*)(pA0 + kn); na0y = *(const float4*)(pA0 + kn + 4);
            na1x = *(const float4*)(pA1 + kn); na1y = *(const float4*)(pA1 + kn + 4);
            nb0x = *(const float4*)(pB0 + kn); nb0y = *(const float4*)(pB0 + kn + 4);
            nb1x = *(const float4*)(pB1 + kn); nb1y = *(const float4*)(pB1 + kn + 4);
        }
        short8 a0h, a0l, a1h, a1l, b0h, b0l, b1h, b1l;
        split8(a0x, a0y, a0h, a0l, nA0);
        split8(a1x, a1y, a1h, a1l, nA1);
        split8(b0x, b0y, b0h, b0l, nB0);
        split8(b1x, b1y, b1h, b1l, nB1);
        // g = hi*hi + hi*lo + lo*hi  (lo*lo dropped, ~2^-32 relative)
        acc00 = __builtin_amdgcn_mfma_f32_16x16x32_bf16(a0h, b0h, acc00, 0, 0, 0);
        acc01 = __builtin_amdgcn_mfma_f32_16x16x32_bf16(a0h, b1h, acc01, 0, 0, 0);
        acc10 = __builtin_amdgcn_mfma_f32_16x16x32_bf16(a1h, b0h, acc10, 0, 0, 0);
        acc11 = __builtin_amdgcn_mfma_f32_16x16x32_bf16(a1h, b1h, acc11, 0, 0, 0);
        acc00 = __builtin_amdgcn_mfma_f32_16x16x32_bf16(a0h, b0l, acc00, 0, 0, 0);
        acc01 = __builtin_amdgcn_mfma_f32_16x16x32_bf16(a0h, b1l, acc01, 0, 0, 0);
        acc10 = __builtin_amdgcn_mfma_f32_16x16x32_bf16(a1h, b0l, acc10, 0, 0, 0);
        acc11 = __builtin_amdgcn_mfma_f32_16x16x32_bf16(a1h, b1l, acc11, 0, 0, 0);
        acc00 = __builtin_amdgcn_mfma_f32_16x16x32_bf16(a0l, b0h, acc00, 0, 0, 0);
        acc01 = __builtin_amdgcn_mfma_f32_16x16x32_bf16(a0l, b1h, acc01, 0, 0, 0);
        acc10 = __builtin_amdgcn_mfma_f32_16x16x32_bf16(a1l, b0h, acc10, 0, 0, 0);
        acc11 = __builtin_amdgcn_mfma_f32_16x16x32_bf16(a1l, b1h, acc11, 0, 0, 0);
        a0x = na0x; a0y = na0y; a1x = na1x; a1y = na1y;
        b0x = nb0x; b0y = nb0y; b1x = nb1x; b1y = nb1y;
    }

    // norms: row ib+r covered by lanes {r, r+16, r+32, r+48} (disjoint k) -> reduce
    nA0 += __shfl_xor(nA0, 16); nA0 += __shfl_xor(nA0, 32);
    nA1 += __shfl_xor(nA1, 16); nA1 += __shfl_xor(nA1, 32);
    nB0 += __shfl_xor(nB0, 16); nB0 += __shfl_xor(nB0, 32);
    nB1 += __shfl_xor(nB1, 16); nB1 += __shfl_xor(nB1, 32);

    // C/D layout (verified R5): col = lane&15, row = half*4 + reg
    const int jc0 = jb + r, jc1 = jb + 16 + r;
    const float nj0 = nB0, nj1 = nB1;
#pragma unroll
    for (int p = 0; p < 4; p++) {
        const int ir0 = ib + half * 4 + p;
        const int ir1 = ir0 + 16;
        const float ni0 = __shfl(nA0, half * 4 + p);   // lane (half*4+p) holds row ib+half*4+p
        const float ni1 = __shfl(nA1, half * 4 + p);
        Dm[(size_t)ir0 * BN + jc0] = dist_val(ni0 + nj0 - 2.f * acc00[p], ir0 == jc0);
        Dm[(size_t)ir0 * BN + jc1] = dist_val(ni0 + nj1 - 2.f * acc01[p], ir0 == jc1);
        Dm[(size_t)ir1 * BN + jc0] = dist_val(ni1 + nj0 - 2.f * acc10[p], ir1 == jc0);
        Dm[(size_t)ir1 * BN + jc1] = dist_val(ni1 + nj1 - 2.f * acc11[p], ir1 == jc1);
    }
}

// ---------------- kernel 2: triplet (R4-proven ballot compaction) ------------
__global__ void triplet_kernel(const float* __restrict__ Dm, const unsigned* __restrict__ masks,
                               float* __restrict__ accum) {
    __shared__ float pos[BN];
    __shared__ float neg[BN];
    __shared__ int pcnt, ncnt;
    __shared__ float wsum[4];
    __shared__ unsigned wcnt[4];
    const int i = blockIdx.x;
    const int t = threadIdx.x;          // 256
    const int lane = t & 63;
    const int w = t >> 6;
    if (t == 0) { pcnt = 0; ncnt = 0; }
    __syncthreads();
    const unsigned mi = masks[i];
    const float* drow = Dm + (size_t)i * BN;
    const unsigned long long ltmask = (1ull << lane) - 1ull;

    for (int j = t; j < BN; j += 256) {
        float dj = drow[j];
        bool isp = (mi & masks[j]) != 0u;
        unsigned long long bal = __ballot(isp);
        int np = __popcll(bal);
        if (np > 0) {
            int ldr = __ffsll((unsigned long long)bal) - 1;
            int base = 0;
            if (lane == ldr) base = atomicAdd(&pcnt, np);
            base = __shfl(base, ldr);
            if (isp) pos[base + __popcll(bal & ltmask)] = dj;
        }
        unsigned long long nbal = ~bal;
        int nn = 64 - np;
        if (nn > 0) {
            int ldr = __ffsll((unsigned long long)nbal) - 1;
            int base = 0;
            if (lane == ldr) base = atomicAdd(&ncnt, nn);
            base = __shfl(base, ldr);
            if (!isp) neg[base + __popcll(nbal & ltmask)] = dj;
        }
    }
    __syncthreads();

    const int P = pcnt, N = ncnt;
    float sum = 0.f;
    unsigned cnt = 0;
    for (int p = t; p < P; p += 256) {
        float a = pos[p];
        for (int n = 0; n < N; n++) {
            float v = a - neg[n];
            sum += fmaxf(v, 0.0f);
            cnt += (v > 1e-16f) ? 1u : 0u;
        }
    }
#pragma unroll
    for (int off = 32; off > 0; off >>= 1) {
        sum += __shfl_down(sum, off);
        cnt += __shfl_down(cnt, off);
    }
    if (lane == 0) { wsum[w] = sum; wcnt[w] = cnt; }
    __syncthreads();
    if (t == 0) {
        sum = wsum[0] + wsum[1] + wsum[2] + wsum[3];
        cnt = wcnt[0] + wcnt[1] + wcnt[2] + wcnt[3];
        if (sum != 0.f || cnt != 0u) {
            atomicAdd(&accum[0], sum);
            atomicAdd(&((unsigned*)accum)[1], cnt);
        }
    }
}

// ---------------- kernel 3: finalize -----------------------------------------
__global__ void finalize_kernel(const float* __restrict__ accum, float* __restrict__ out) {
    if (threadIdx.x == 0) {
        float s = accum[0];
        float c = (float)((const unsigned*)accum)[1];
        out[0] = s / (c + 1e-16f);
    }
}

extern "C" void kernel_launch(void* const* d_in, const int* in_sizes, int n_in,
                              void* d_out, int out_size, void* d_ws, size_t ws_size,
                              hipStream_t stream) {
    const float* src    = (const float*)d_in[0];
    const int*   labels = (const int*)d_in[1];
    float* ws = (float*)d_ws;
    unsigned* masks = (unsigned*)ws;
    float*    Dm    = ws + BN;
    float*    accum = ws + BN + (size_t)BN * BN;

    hipLaunchKernelGGL(dist_fused_kernel, dim3(16, 16), dim3(64),  0, stream,
                       src, labels, masks, Dm, accum);
    hipLaunchKernelGGL(triplet_kernel,    dim3(BN),     dim3(256), 0, stream,
                       Dm, masks, accum);
    hipLaunchKernelGGL(finalize_kernel,   dim3(1),      dim3(64),  0, stream,
                       accum, (float*)d_out);
}

// Round 7
// 74.093 us; speedup vs baseline: 1.0324x; 1.0324x over previous
//
#include <hip/hip_runtime.h>

#define BN 512   // batch
#define DD 512   // feature dim
#define LL 24    // label dim

typedef unsigned short u16;
typedef __attribute__((ext_vector_type(8))) short short8;  // 8 bf16 = 4 VGPR
typedef __attribute__((ext_vector_type(4))) float f32x4;

// ws layout (float words):
//   [0,512)              masks (u32)
//   [512, 512+262144)    Dm (f32, 512x512)
//   [262656]             accum: [0]=sum(f32) [1]=cnt(u32)

__device__ __forceinline__ u16 bf16_rn(float f) {
    unsigned u = __float_as_uint(f);
    return (u16)((u + 0x7FFFu + ((u >> 16) & 1u)) >> 16);
}

__device__ __forceinline__ float dist_val(float d2, bool diag) {
    d2 = fmaxf(d2, 0.0f);
    float d = sqrtf(d2);
    return diag ? 0.0f : d;
}

// pack 8 f32 -> bf16 fragment (round-to-nearest), accumulate sum of squares
__device__ __forceinline__ void pack8(float4 x, float4 y, short8& h, float& nrm) {
    float f[8] = {x.x, x.y, x.z, x.w, y.x, y.y, y.z, y.w};
#pragma unroll
    for (int e = 0; e < 8; e++) {
        nrm = fmaf(f[e], f[e], nrm);
        h[e] = (short)bf16_rn(f[e]);
    }
}

// ---------- kernel 1: fused prep + pure-bf16 MFMA dist -----------------------
__global__ __launch_bounds__(64) void dist_fused_kernel(
    const float* __restrict__ S, const int* __restrict__ labels,
    unsigned* __restrict__ masks, float* __restrict__ Dm, float* __restrict__ accum)
{
    const int l    = threadIdx.x;
    const int r    = l & 15;        // fragment row (A.m / B.n), also C.col
    const int half = l >> 4;        // k-base half*8; C.row base half*4
    const int jb = blockIdx.x * 32;
    const int ib = blockIdx.y * 32;
    const int kb = half * 8;

    // masks (y==0 blocks, 32 rows each) + accum zero (block 0,0)
    if (blockIdx.y == 0) {
        if (l < 32) {
            const int row = blockIdx.x * 32 + l;
            const int* lab = labels + row * LL;
            unsigned m = 0;
#pragma unroll
            for (int q = 0; q < LL; q++) m |= (lab[q] != 0 ? 1u : 0u) << q;
            masks[row] = m;
        }
        if (blockIdx.x == 0 && l == 0) { accum[0] = 0.0f; ((unsigned*)accum)[1] = 0u; }
    }

    const float* pA0 = S + (size_t)(ib + r)      * DD + kb;
    const float* pA1 = S + (size_t)(ib + 16 + r) * DD + kb;
    const float* pB0 = S + (size_t)(jb + r)      * DD + kb;
    const float* pB1 = S + (size_t)(jb + 16 + r) * DD + kb;

    f32x4 acc00 = {0.f,0.f,0.f,0.f}, acc01 = acc00, acc10 = acc00, acc11 = acc00;
    float nA0 = 0.f, nA1 = 0.f, nB0 = 0.f, nB1 = 0.f;

    float4 a0x = *(const float4*)pA0, a0y = *(const float4*)(pA0 + 4);
    float4 a1x = *(const float4*)pA1, a1y = *(const float4*)(pA1 + 4);
    float4 b0x = *(const float4*)pB0, b0y = *(const float4*)(pB0 + 4);
    float4 b1x = *(const float4*)pB1, b1y = *(const float4*)(pB1 + 4);

    for (int k0 = 0; k0 < DD; k0 += 32) {
        float4 na0x, na0y, na1x, na1y, nb0x, nb0y, nb1x, nb1y;
        const int kn = k0 + 32;
        if (kn < DD) {              // uniform: prefetch next k-step
            na0x = *(const float4*)(pA0 + kn); na0y = *(const float4*)(pA0 + kn + 4);
            na1x = *(const float4*)(pA1 + kn); na1y = *(const float4*)(pA1 + kn + 4);
            nb0x = *(const float4*)(pB0 + kn); nb0y = *(const float4*)(pB0 + kn + 4);
            nb1x = *(const float4*)(pB1 + kn); nb1y = *(const float4*)(pB1 + kn + 4);
        }
        short8 a0h, a1h, b0h, b1h;
        pack8(a0x, a0y, a0h, nA0);
        pack8(a1x, a1y, a1h, nA1);
        pack8(b0x, b0y, b0h, nB0);
        pack8(b1x, b1y, b1h, nB1);
        acc00 = __builtin_amdgcn_mfma_f32_16x16x32_bf16(a0h, b0h, acc00, 0, 0, 0);
        acc01 = __builtin_amdgcn_mfma_f32_16x16x32_bf16(a0h, b1h, acc01, 0, 0, 0);
        acc10 = __builtin_amdgcn_mfma_f32_16x16x32_bf16(a1h, b0h, acc10, 0, 0, 0);
        acc11 = __builtin_amdgcn_mfma_f32_16x16x32_bf16(a1h, b1h, acc11, 0, 0, 0);
        a0x = na0x; a0y = na0y; a1x = na1x; a1y = na1y;
        b0x = nb0x; b0y = nb0y; b1x = nb1x; b1y = nb1y;
    }

    // norms: row ib+r covered by lanes {r, r+16, r+32, r+48} (disjoint k) -> reduce
    nA0 += __shfl_xor(nA0, 16); nA0 += __shfl_xor(nA0, 32);
    nA1 += __shfl_xor(nA1, 16); nA1 += __shfl_xor(nA1, 32);
    nB0 += __shfl_xor(nB0, 16); nB0 += __shfl_xor(nB0, 32);
    nB1 += __shfl_xor(nB1, 16); nB1 += __shfl_xor(nB1, 32);

    // C/D layout (verified R5/R6): col = lane&15, row = half*4 + reg
    const int jc0 = jb + r, jc1 = jb + 16 + r;
    const float nj0 = nB0, nj1 = nB1;
#pragma unroll
    for (int p = 0; p < 4; p++) {
        const int ir0 = ib + half * 4 + p;
        const int ir1 = ir0 + 16;
        const float ni0 = __shfl(nA0, half * 4 + p);   // lane (half*4+p) holds row ib+half*4+p
        const float ni1 = __shfl(nA1, half * 4 + p);
        Dm[(size_t)ir0 * BN + jc0] = dist_val(ni0 + nj0 - 2.f * acc00[p], ir0 == jc0);
        Dm[(size_t)ir0 * BN + jc1] = dist_val(ni0 + nj1 - 2.f * acc01[p], ir0 == jc1);
        Dm[(size_t)ir1 * BN + jc0] = dist_val(ni1 + nj0 - 2.f * acc10[p], ir1 == jc0);
        Dm[(size_t)ir1 * BN + jc1] = dist_val(ni1 + nj1 - 2.f * acc11[p], ir1 == jc1);
    }
}

// ---------------- kernel 2: triplet (R4-proven ballot compaction) ------------
__global__ void triplet_kernel(const float* __restrict__ Dm, const unsigned* __restrict__ masks,
                               float* __restrict__ accum) {
    __shared__ float pos[BN];
    __shared__ float neg[BN];
    __shared__ int pcnt, ncnt;
    __shared__ float wsum[4];
    __shared__ unsigned wcnt[4];
    const int i = blockIdx.x;
    const int t = threadIdx.x;          // 256
    const int lane = t & 63;
    const int w = t >> 6;
    if (t == 0) { pcnt = 0; ncnt = 0; }
    __syncthreads();
    const unsigned mi = masks[i];
    const float* drow = Dm + (size_t)i * BN;
    const unsigned long long ltmask = (1ull << lane) - 1ull;

    for (int j = t; j < BN; j += 256) {
        float dj = drow[j];
        bool isp = (mi & masks[j]) != 0u;
        unsigned long long bal = __ballot(isp);
        int np = __popcll(bal);
        if (np > 0) {
            int ldr = __ffsll((unsigned long long)bal) - 1;
            int base = 0;
            if (lane == ldr) base = atomicAdd(&pcnt, np);
            base = __shfl(base, ldr);
            if (isp) pos[base + __popcll(bal & ltmask)] = dj;
        }
        unsigned long long nbal = ~bal;
        int nn = 64 - np;
        if (nn > 0) {
            int ldr = __ffsll((unsigned long long)nbal) - 1;
            int base = 0;
            if (lane == ldr) base = atomicAdd(&ncnt, nn);
            base = __shfl(base, ldr);
            if (!isp) neg[base + __popcll(nbal & ltmask)] = dj;
        }
    }
    __syncthreads();

    const int P = pcnt, N = ncnt;
    float sum = 0.f;
    unsigned cnt = 0;
    for (int p = t; p < P; p += 256) {
        float a = pos[p];
        for (int n = 0; n < N; n++) {
            float v = a - neg[n];
            sum += fmaxf(v, 0.0f);
            cnt += (v > 1e-16f) ? 1u : 0u;
        }
    }
#pragma unroll
    for (int off = 32; off > 0; off >>= 1) {
        sum += __shfl_down(sum, off);
        cnt += __shfl_down(cnt, off);
    }
    if (lane == 0) { wsum[w] = sum; wcnt[w] = cnt; }
    __syncthreads();
    if (t == 0) {
        sum = wsum[0] + wsum[1] + wsum[2] + wsum[3];
        cnt = wcnt[0] + wcnt[1] + wcnt[2] + wcnt[3];
        if (sum != 0.f || cnt != 0u) {
            atomicAdd(&accum[0], sum);
            atomicAdd(&((unsigned*)accum)[1], cnt);
        }
    }
}

// ---------------- kernel 3: finalize -----------------------------------------
__global__ void finalize_kernel(const float* __restrict__ accum, float* __restrict__ out) {
    if (threadIdx.x == 0) {
        float s = accum[0];
        float c = (float)((const unsigned*)accum)[1];
        out[0] = s / (c + 1e-16f);
    }
}

extern "C" void kernel_launch(void* const* d_in, const int* in_sizes, int n_in,
                              void* d_out, int out_size, void* d_ws, size_t ws_size,
                              hipStream_t stream) {
    const float* src    = (const float*)d_in[0];
    const int*   labels = (const int*)d_in[1];
    float* ws = (float*)d_ws;
    unsigned* masks = (unsigned*)ws;
    float*    Dm    = ws + BN;
    float*    accum = ws + BN + (size_t)BN * BN;

    hipLaunchKernelGGL(dist_fused_kernel, dim3(16, 16), dim3(64),  0, stream,
                       src, labels, masks, Dm, accum);
    hipLaunchKernelGGL(triplet_kernel,    dim3(BN),     dim3(256), 0, stream,
                       Dm, masks, accum);
    hipLaunchKernelGGL(finalize_kernel,   dim3(1),      dim3(64),  0, stream,
                       accum, (float*)d_out);
}

// Round 9
// 68.657 us; speedup vs baseline: 1.1142x; 1.0792x over previous
//
#include <hip/hip_runtime.h>
#include <hip/hip_bf16.h>

#define BN 512   // batch
#define DD 512   // feature dim
#define LL 24    // label dim

typedef unsigned short u16;
typedef __attribute__((ext_vector_type(8))) short short8;  // 8 bf16 = 4 VGPR
typedef __attribute__((ext_vector_type(4))) float f32x4;

// ws layout (float words):
//   [0,512)              masks (u32)
//   [512, 512+262144)    Dm (f32, 512x512)
//   [262656]             accum: [0]=sum(f32) [1]=cnt(u32)

__device__ __forceinline__ float dist_val(float d2, bool diag) {
    d2 = fmaxf(d2, 0.0f);
    float d = sqrtf(d2);
    return diag ? 0.0f : d;
}

__device__ __forceinline__ unsigned pk_bf16(float lo, float hi) {
    __hip_bfloat162 p = __float22bfloat162_rn(make_float2(lo, hi));
    unsigned u;
    __builtin_memcpy(&u, &p, 4);     // type-pun; bit_cast rejects non-trivial ctor
    return u;
}

// pack 8 f32 -> bf16 fragment via v_cvt_pk_bf16_f32, accumulate sum of squares
__device__ __forceinline__ short8 pack8_pk(float4 x, float4 y, float& nrm) {
    nrm = fmaf(x.x, x.x, nrm); nrm = fmaf(x.y, x.y, nrm);
    nrm = fmaf(x.z, x.z, nrm); nrm = fmaf(x.w, x.w, nrm);
    nrm = fmaf(y.x, y.x, nrm); nrm = fmaf(y.y, y.y, nrm);
    nrm = fmaf(y.z, y.z, nrm); nrm = fmaf(y.w, y.w, nrm);
    union { uint4 u; short8 s; } cv;
    cv.u.x = pk_bf16(x.x, x.y);
    cv.u.y = pk_bf16(x.z, x.w);
    cv.u.z = pk_bf16(y.x, y.y);
    cv.u.w = pk_bf16(y.z, y.w);
    return cv.s;
}

// ---------- kernel 1: fused prep + bf16 MFMA dist, 16x16 tile per wave -------
__global__ __launch_bounds__(64) void dist_fused_kernel(
    const float* __restrict__ S, const int* __restrict__ labels,
    unsigned* __restrict__ masks, float* __restrict__ Dm, float* __restrict__ accum)
{
    const int l    = threadIdx.x;
    const int r    = l & 15;        // fragment row (A.m / B.n), also C.col
    const int half = l >> 4;        // k-base half*8; C.row base half*4
    const int jb = blockIdx.x * 16;
    const int ib = blockIdx.y * 16;
    const int kb = half * 8;

    // masks (y==0 blocks, 16 rows each) + accum zero (block 0,0)
    if (blockIdx.y == 0) {
        if (l < 16) {
            const int row = blockIdx.x * 16 + l;
            const int* lab = labels + row * LL;
            unsigned m = 0;
#pragma unroll
            for (int q = 0; q < LL; q++) m |= (lab[q] != 0 ? 1u : 0u) << q;
            masks[row] = m;
        }
        if (blockIdx.x == 0 && l == 0) { accum[0] = 0.0f; ((unsigned*)accum)[1] = 0u; }
    }

    const float* pA = S + (size_t)(ib + r) * DD + kb;
    const float* pB = S + (size_t)(jb + r) * DD + kb;

    f32x4 acc = {0.f, 0.f, 0.f, 0.f};
    float nA = 0.f, nB = 0.f;

    float4 ax = *(const float4*)pA, ay = *(const float4*)(pA + 4);
    float4 bx = *(const float4*)pB, by = *(const float4*)(pB + 4);

    for (int k0 = 0; k0 < DD; k0 += 32) {
        float4 nax, nay, nbx, nby;
        const int kn = k0 + 32;
        if (kn < DD) {              // uniform: prefetch next k-step
            nax = *(const float4*)(pA + kn); nay = *(const float4*)(pA + kn + 4);
            nbx = *(const float4*)(pB + kn); nby = *(const float4*)(pB + kn + 4);
        }
        short8 af = pack8_pk(ax, ay, nA);
        short8 bf = pack8_pk(bx, by, nB);
        acc = __builtin_amdgcn_mfma_f32_16x16x32_bf16(af, bf, acc, 0, 0, 0);
        ax = nax; ay = nay; bx = nbx; by = nby;
    }

    // norms: row ib+r covered by lanes {r, r+16, r+32, r+48} (disjoint k) -> reduce
    nA += __shfl_xor(nA, 16); nA += __shfl_xor(nA, 32);
    nB += __shfl_xor(nB, 16); nB += __shfl_xor(nB, 32);

    // C/D layout (verified R5-R7): col = lane&15, row = half*4 + reg
    const int jc = jb + r;
    const float nj = nB;
#pragma unroll
    for (int p = 0; p < 4; p++) {
        const int ir = ib + half * 4 + p;
        const float ni = __shfl(nA, half * 4 + p);   // lane (half*4+p) holds row ib+half*4+p
        Dm[(size_t)ir * BN + jc] = dist_val(ni + nj - 2.f * acc[p], ir == jc);
    }
}

// ---------------- kernel 2: triplet (R4-proven ballot compaction) ------------
__global__ void triplet_kernel(const float* __restrict__ Dm, const unsigned* __restrict__ masks,
                               float* __restrict__ accum) {
    __shared__ float pos[BN];
    __shared__ float neg[BN];
    __shared__ int pcnt, ncnt;
    __shared__ float wsum[4];
    __shared__ unsigned wcnt[4];
    const int i = blockIdx.x;
    const int t = threadIdx.x;          // 256
    const int lane = t & 63;
    const int w = t >> 6;
    if (t == 0) { pcnt = 0; ncnt = 0; }
    __syncthreads();
    const unsigned mi = masks[i];
    const float* drow = Dm + (size_t)i * BN;
    const unsigned long long ltmask = (1ull << lane) - 1ull;

    for (int j = t; j < BN; j += 256) {
        float dj = drow[j];
        bool isp = (mi & masks[j]) != 0u;
        unsigned long long bal = __ballot(isp);
        int np = __popcll(bal);
        if (np > 0) {
            int ldr = __ffsll((unsigned long long)bal) - 1;
            int base = 0;
            if (lane == ldr) base = atomicAdd(&pcnt, np);
            base = __shfl(base, ldr);
            if (isp) pos[base + __popcll(bal & ltmask)] = dj;
        }
        unsigned long long nbal = ~bal;
        int nn = 64 - np;
        if (nn > 0) {
            int ldr = __ffsll((unsigned long long)nbal) - 1;
            int base = 0;
            if (lane == ldr) base = atomicAdd(&ncnt, nn);
            base = __shfl(base, ldr);
            if (!isp) neg[base + __popcll(nbal & ltmask)] = dj;
        }
    }
    __syncthreads();

    const int P = pcnt, N = ncnt;
    float sum = 0.f;
    unsigned cnt = 0;
    for (int p = t; p < P; p += 256) {
        float a = pos[p];
        for (int n = 0; n < N; n++) {
            float v = a - neg[n];
            sum += fmaxf(v, 0.0f);
            cnt += (v > 1e-16f) ? 1u : 0u;
        }
    }
#pragma unroll
    for (int off = 32; off > 0; off >>= 1) {
        sum += __shfl_down(sum, off);
        cnt += __shfl_down(cnt, off);
    }
    if (lane == 0) { wsum[w] = sum; wcnt[w] = cnt; }
    __syncthreads();
    if (t == 0) {
        sum = wsum[0] + wsum[1] + wsum[2] + wsum[3];
        cnt = wcnt[0] + wcnt[1] + wcnt[2] + wcnt[3];
        if (sum != 0.f || cnt != 0u) {
            atomicAdd(&accum[0], sum);
            atomicAdd(&((unsigned*)accum)[1], cnt);
        }
    }
}

// ---------------- kernel 3: finalize -----------------------------------------
__global__ void finalize_kernel(const float* __restrict__ accum, float* __restrict__ out) {
    if (threadIdx.x == 0) {
        float s = accum[0];
        float c = (float)((const unsigned*)accum)[1];
        out[0] = s / (c + 1e-16f);
    }
}

extern "C" void kernel_launch(void* const* d_in, const int* in_sizes, int n_in,
                              void* d_out, int out_size, void* d_ws, size_t ws_size,
                              hipStream_t stream) {
    const float* src    = (const float*)d_in[0];
    const int*   labels = (const int*)d_in[1];
    float* ws = (float*)d_ws;
    unsigned* masks = (unsigned*)ws;
    float*    Dm    = ws + BN;
    float*    accum = ws + BN + (size_t)BN * BN;

    hipLaunchKernelGGL(dist_fused_kernel, dim3(32, 32), dim3(64),  0, stream,
                       src, labels, masks, Dm, accum);
    hipLaunchKernelGGL(triplet_kernel,    dim3(BN),     dim3(256), 0, stream,
                       Dm, masks, accum);
    hipLaunchKernelGGL(finalize_kernel,   dim3(1),      dim3(64),  0, stream,
                       accum, (float*)d_out);
}